// Round 14
// baseline (2117.380 us; speedup 1.0000x reference)
//
#include <hip/hip_runtime.h>

// GRU (Flax GRUCell), B=64 T=512 D=512 H=512, fp32 in/out, fp16 MFMA compute.
//
// r14 = r13 with ONE bug fixed: gemm_gi epilogue read O_l u64s at row*12+seg;
// O_l is [16][96] fp16 -> row stride is 24 u64s. (row*24+seg.) That bug wrote
// gi from wrong LDS locations -> absmax 1.91. All else identical to r13:
// Precompute gi = x@Wi + bi (parallel MFMA GEMM, 100MB ws region, ws_size-
// gated with r8-verbatim fallback). Recurrence needs only Wh in LDS -> each
// block owns 32 columns -> 4 groups x 16 RANKS (64 blocks): half the pollers
// (fabric congestion = the proven limiter r7/r9/r10/r12), tail over 16 not
// 32 blocks, combine reads gi directly (x-GEMM off the critical path).
// Exchange transport byte-compatible with r8 (4x HW-proven): sentinel-coded
// data polling on sc1, 4-slot rotation, owner resets own region 2 slots
// ahead, single poller wave + XOR-swizzled LDS broadcast, bounded loops.

#define BSZ 64
#define TLEN 512
#define DDIM 512
#define HDIM 512
#define SENT32 0x40004000u
#define SENT64 0x4000400040004000ull
#define GUARD (1 << 16)

typedef _Float16 half8 __attribute__((ext_vector_type(8)));
typedef _Float16 half4v __attribute__((ext_vector_type(4)));
typedef float f32x4 __attribute__((ext_vector_type(4)));

__device__ __forceinline__ float sigmf(float v) { return 1.f / (1.f + __expf(-v)); }
__device__ __forceinline__ float lo16(unsigned u) {
  unsigned short s = (unsigned short)(u & 0xffffu);
  _Float16 f;
  __builtin_memcpy(&f, &s, 2);
  return (float)f;
}
__device__ __forceinline__ float hi16(unsigned u) {
  unsigned short s = (unsigned short)(u >> 16);
  _Float16 f;
  __builtin_memcpy(&f, &s, 2);
  return (float)f;
}

// per-lane dirty mask: dword low half == sentinel? (4B writer stores cover
// 2 fp16 atomically -> per-dword low-half check is partial-write-safe)
__device__ __forceinline__ unsigned chk16(const half8* ah) {
  unsigned dirty = 0;
#pragma unroll
  for (int kt = 0; kt < 16; ++kt) {
    uint4 c;
    __builtin_memcpy(&c, &ah[kt], 16);
    unsigned bad = ((c.x & 0xFFFFu) == 0x4000u) | ((c.y & 0xFFFFu) == 0x4000u) |
                   ((c.z & 0xFFFFu) == 0x4000u) | ((c.w & 0xFFFFu) == 0x4000u);
    dirty |= bad << kt;
  }
  return dirty;
}

// 16-load pipelined sweep over 4 base ptrs (1KB chunks), one vmcnt.
#define SWEEP16(AH, P0, P1, P2, P3)                                           \
  asm volatile(                                                               \
      "global_load_dwordx4 %0,  %16, off sc1\n\t"                             \
      "global_load_dwordx4 %1,  %16, off offset:1024 sc1\n\t"                 \
      "global_load_dwordx4 %2,  %16, off offset:2048 sc1\n\t"                 \
      "global_load_dwordx4 %3,  %16, off offset:3072 sc1\n\t"                 \
      "global_load_dwordx4 %4,  %17, off sc1\n\t"                             \
      "global_load_dwordx4 %5,  %17, off offset:1024 sc1\n\t"                 \
      "global_load_dwordx4 %6,  %17, off offset:2048 sc1\n\t"                 \
      "global_load_dwordx4 %7,  %17, off offset:3072 sc1\n\t"                 \
      "global_load_dwordx4 %8,  %18, off sc1\n\t"                             \
      "global_load_dwordx4 %9,  %18, off offset:1024 sc1\n\t"                 \
      "global_load_dwordx4 %10, %18, off offset:2048 sc1\n\t"                 \
      "global_load_dwordx4 %11, %18, off offset:3072 sc1\n\t"                 \
      "global_load_dwordx4 %12, %19, off sc1\n\t"                             \
      "global_load_dwordx4 %13, %19, off offset:1024 sc1\n\t"                 \
      "global_load_dwordx4 %14, %19, off offset:2048 sc1\n\t"                 \
      "global_load_dwordx4 %15, %19, off offset:3072 sc1\n\t"                 \
      "s_waitcnt vmcnt(0)"                                                    \
      : "=&v"(AH[0]), "=&v"(AH[1]), "=&v"(AH[2]), "=&v"(AH[3]), "=&v"(AH[4]), \
        "=&v"(AH[5]), "=&v"(AH[6]), "=&v"(AH[7]), "=&v"(AH[8]), "=&v"(AH[9]), \
        "=&v"(AH[10]), "=&v"(AH[11]), "=&v"(AH[12]), "=&v"(AH[13]),           \
        "=&v"(AH[14]), "=&v"(AH[15])                                          \
      : "v"(P0), "v"(P1), "v"(P2), "v"(P3))

// ======================= FAST PATH (ws >= 101MB) =========================

// sentinel-fill exchange (4 groups x 64KB)
__global__ void setup_fast(unsigned* __restrict__ exch) {
  size_t gid = (size_t)blockIdx.x * blockDim.x + threadIdx.x;
  size_t stride = (size_t)gridDim.x * blockDim.x;
  for (size_t i = gid; i < 65536; i += stride) exch[i] = SENT32;
}

// gi[m][n] = sum_k x[m][k] * Wi[k][n] + bi[n], fp16 out. M=32768 N=1536 K=512.
// grid 512 = 16 colblocks(96) x 32 m-partitions(64 chunks of 16 rows each).
__global__ __launch_bounds__(384, 1) void gemm_gi(const float* __restrict__ x,
                                                  const float* __restrict__ Wi,
                                                  const float* __restrict__ bi,
                                                  _Float16* __restrict__ gi) {
  __shared__ _Float16 W_l[96 * 512];  // 96KB, XOR-swizzled rows
  __shared__ _Float16 A_l[16 * 512];  // 16KB
  __shared__ _Float16 O_l[16 * 96];   // 3KB epilogue transpose

  const int tid = threadIdx.x;
  const int lane = tid & 63;
  const int wid = tid >> 6;  // 0..5
  const int cb = blockIdx.x & 15;
  const int mp = blockIdx.x >> 4;
  const int n0 = cb * 96;

  // stage Wi slice (rows r=0..95 <-> n = n0+r), swizzled like Wh in recurrence
  for (int idx = tid; idx < 96 * 512; idx += 384) {
    int k = idx / 96;
    int r = idx - k * 96;
    int phys = (r << 10) | ((((k >> 3) << 4) ^ ((r & 7) << 4))) | ((k & 7) << 1);
    *(_Float16*)((char*)W_l + phys) = (_Float16)Wi[(size_t)k * 1536 + n0 + r];
  }
  const int ar = lane & 15;
  const int kg = lane >> 4;
  const int wrow = wid * 16 + ar;
  const int axor = (ar & 7) << 4;
  const float bin = bi[n0 + wid * 16 + ar];
  __syncthreads();

  const float4* x4 = (const float4*)x;
  for (int mc = 0; mc < 64; ++mc) {
    const int m0 = (mp * 64 + mc) * 16;
    // stage A: 16 rows x 512 fp32 -> fp16 swizzled (quad = 4 k's = 8B chunk)
    for (int i = tid; i < 2048; i += 384) {
      int r = i >> 7, kq = i & 127, k = kq * 4;
      float4 v = x4[(size_t)(m0 + r) * 128 + kq];
      half4v o = {(_Float16)v.x, (_Float16)v.y, (_Float16)v.z, (_Float16)v.w};
      int phys = (r << 10) | ((((k >> 3) << 4) ^ ((r & 7) << 4))) | ((k & 7) << 1);
      *(half4v*)((char*)A_l + phys) = o;
    }
    __syncthreads();
    f32x4 acc = {0.f, 0.f, 0.f, 0.f};
#pragma unroll
    for (int kt = 0; kt < 16; ++kt) {
      const int off = (((kt * 4 + kg) << 4) ^ axor);
      half8 a = *(const half8*)((const char*)A_l + (ar << 10) + off);
      half8 b = *(const half8*)((const char*)W_l + (wrow << 10) + off);
      acc = __builtin_amdgcn_mfma_f32_16x16x32_f16(a, b, acc, 0, 0, 0);
    }
#pragma unroll
    for (int q = 0; q < 4; ++q)
      O_l[(kg * 4 + q) * 96 + wid * 16 + ar] = (_Float16)(acc[q] + bin);
    __syncthreads();
    // coalesced write: 16 rows x 192B; 24 threads/row x 8B.
    // O_l row stride = 96 fp16 = 24 u64 -> index row*24+seg (r13 bug: *12)
    {
      int row = tid / 24, seg = tid % 24;
      if (row < 16) {
        *(unsigned long long*)(gi + (size_t)(m0 + row) * 1536 + n0 + seg * 4) =
            ((const unsigned long long*)O_l)[row * 24 + seg];
      }
    }
    __syncthreads();  // O_l/A_l reuse fence for next chunk
  }
}

// recurrence: 4 groups x 16 batches x 16 ranks (32 cols each). 384 thr.
// w5 = poll+stage, w4 = slot reset, w0..3 = combine+publish+out; all 6 waves
// run the h-GEMM (96 output rows = 6 wave-tiles).
__global__ __launch_bounds__(384, 1) void gru_rec16(
    const _Float16* __restrict__ gi, const float* __restrict__ Wh,
    const float* __restrict__ bhn, char* __restrict__ exch,
    float* __restrict__ out) {
  __shared__ _Float16 Wh_l[96 * 512];  // 96KB
  __shared__ _Float16 Ah_l[16 * 512];  // 16KB
  __shared__ float Gh_l[2][6 * 256];   // 12KB

  const int tid = threadIdx.x;
  const int lane = tid & 63;
  const int wid = tid >> 6;  // 0..5
  const int g = blockIdx.x >> 4;
  const int rank = blockIdx.x & 15;
  const int c0 = rank * 32;
  char* const exg = exch + (size_t)g * 65536;  // 4 slots x 16KB

  // stage Wh slice (96 rows: gate = r>>5, col = c0 + (r&31)), swizzled
  for (int idx = tid; idx < 96 * 512; idx += 384) {
    int k = idx / 96;
    int r = idx - k * 96;
    int col = (r >> 5) * 512 + c0 + (r & 31);
    int phys = (r << 10) | ((((k >> 3) << 4) ^ ((r & 7) << 4))) | ((k & 7) << 1);
    *(_Float16*)((char*)Wh_l + phys) = (_Float16)Wh[(size_t)k * 1536 + col];
  }

  // combine mapping (waves 0..3): 2 elems/lane: batch m, cols {c, c+1}
  const int e0 = ((wid & 3) * 64 + lane) * 2;
  const int m = e0 >> 5;   // 0..15
  const int c = e0 & 31;   // even
  const int bglob = g * 16 + m;
  const _Float16* const giR =
      gi + (size_t)bglob * TLEN * 1536 + c0 + c;  // + t*1536
  const _Float16* const giZ = giR + 512;
  const _Float16* const giN = giR + 1024;
  float bh2[2];
  bh2[0] = bhn[c0 + c];
  bh2[1] = bhn[c0 + c + 1];
  float hreg[2] = {0.f, 0.f};
  __syncthreads();  // weights staged

  const int ar = lane & 15;
  const int kg = lane >> 4;
  const int wrow = wid * 16 + ar;
  const int axor = (ar & 7) << 4;
  const int abase = ar << 10;
  // slot layout: [rank(=chunk kt)][batch][col]: kt*1024 + m*64 + col*2
  char* const hbase = exg + ar * 64 + kg * 16;

  for (int t = 0; t < TLEN; ++t) {
    // 0. w4: reset own 1KB region in slot t+2 (64 lanes x 16B)
    if (wid == 4) {
      unsigned long long* rst = (unsigned long long*)(exg + ((t + 2) & 3) * 16384 +
                                                      rank * 1024 + lane * 16);
      __hip_atomic_store(rst, SENT64, __ATOMIC_RELAXED, __HIP_MEMORY_SCOPE_AGENT);
      __hip_atomic_store(rst + 1, SENT64, __ATOMIC_RELAXED, __HIP_MEMORY_SCOPE_AGENT);
    }
    // 1. w0-3: prefetch gi pairs (independent of h; done by combine time)
    unsigned ur = 0, uz = 0, un = 0;
    if (wid < 4) {
      const size_t toff = (size_t)t * 1536;
      ur = *(const unsigned*)(giR + toff);
      uz = *(const unsigned*)(giZ + toff);
      un = *(const unsigned*)(giN + toff);
    }
    // 2. w5: poll+stage (r8-proven transport)
    if (wid == 5 && t > 0) {
      char* hb = hbase + (t & 3) * 16384;
      const char* p0 = hb;
      const char* p1 = hb + 4096;
      const char* p2 = hb + 8192;
      const char* p3 = hb + 12288;
      half8 ah[16];
      unsigned dirty;
      int guard = 0;
      do {
        SWEEP16(ah, p0, p1, p2, p3);
        dirty = chk16(ah);
      } while (__any(dirty != 0u) && ++guard < GUARD);  // bounded: no hang
#pragma unroll
      for (int kt = 0; kt < 16; ++kt) {
        *(half8*)((char*)Ah_l + (abase | ((kt * 64 + kg * 16) ^ axor))) = ah[kt];
      }
    }
    __syncthreads();  // barrier1: Ah_l ready (w4 resets drained)

    // 3. h-GEMM (all 6 waves; 96 output rows)
    f32x4 acc_h = {0.f, 0.f, 0.f, 0.f};
    if (t > 0) {
#pragma unroll
      for (int kt = 0; kt < 16; ++kt) {
        half8 a_h = *(const half8*)((const char*)Ah_l +
                                    (abase | ((kt * 64 + kg * 16) ^ axor)));
        const int off = (((kt * 4 + kg) << 4) ^ axor);
        half8 b_h = *(const half8*)((const char*)Wh_l + (wrow << 10) + off);
        acc_h = __builtin_amdgcn_mfma_f32_16x16x32_f16(a_h, b_h, acc_h, 0, 0, 0);
      }
    }
#pragma unroll
    for (int q = 0; q < 4; ++q)
      Gh_l[t & 1][wid * 256 + (kg * 4 + q) * 16 + ar] = acc_h[q];
    __syncthreads();  // barrier2: gates ready

    // 4. w0-3: combine + publish + out (parallel across 4 waves)
    if (wid < 4) {
      const float* GhT = Gh_l[t & 1];
      const int ti = (c >> 4);        // 16-col tile within gate (0 or 1)
      const int cc = c & 15;          // col within tile (even; cc,cc+1 same tile)
      float hn2[2];
      const float gir[2] = {lo16(ur), hi16(ur)};
      const float giz[2] = {lo16(uz), hi16(uz)};
      const float gin[2] = {lo16(un), hi16(un)};
#pragma unroll
      for (int u = 0; u < 2; ++u) {
        const int gidx = m * 16 + cc + u;
        float hr = GhT[(0 * 2 + ti) * 256 + gidx];
        float hz = GhT[(1 * 2 + ti) * 256 + gidx];
        float hn = GhT[(2 * 2 + ti) * 256 + gidx];
        float r = sigmf(gir[u] + hr);
        float z = sigmf(giz[u] + hz);
        float pren = gin[u] + r * (hn + bh2[u]);
        float n = 2.f / (1.f + __expf(-2.f * pren)) - 1.f;
        hn2[u] = (1.f - z) * n + z * hreg[u];
        hreg[u] = hn2[u];
      }
      _Float16 q0 = (_Float16)hn2[0], q1 = (_Float16)hn2[1];
      unsigned pu = ((unsigned)*(unsigned short*)&q1 << 16) | *(unsigned short*)&q0;
      __hip_atomic_store(
          (unsigned*)(exg + ((t + 1) & 3) * 16384 + rank * 1024 + m * 64 + c * 2),
          pu, __ATOMIC_RELAXED, __HIP_MEMORY_SCOPE_AGENT);
      *(float2*)(out + ((size_t)bglob * TLEN + t) * HDIM + c0 + c) =
          make_float2(hn2[0], hn2[1]);
    }
  }
  // carry output
  if (wid < 4) {
    *(float2*)(out + (size_t)BSZ * TLEN * HDIM + (size_t)bglob * HDIM + c0 + c) =
        make_float2(hreg[0], hreg[1]);
  }
}

// ===================== FALLBACK PATH (r8 verbatim) =======================

__global__ void gru_setup(const float* __restrict__ x, _Float16* __restrict__ xb,
                          unsigned* __restrict__ exch) {
  size_t gid = (size_t)blockIdx.x * blockDim.x + threadIdx.x;
  size_t stride = (size_t)gridDim.x * blockDim.x;
  const float4* x4 = (const float4*)x;
  size_t nx4 = (size_t)BSZ * TLEN * DDIM / 4;
  for (size_t i = gid; i < nx4; i += stride) {
    float4 v = x4[i];
    half4v o = {(_Float16)v.x, (_Float16)v.y, (_Float16)v.z, (_Float16)v.w};
    *(half4v*)(xb + 4 * i) = o;
  }
  for (size_t i = gid; i < 65536; i += stride) exch[i] = SENT32;
}

__global__ __launch_bounds__(192, 1) void gru_rec(
    const _Float16* __restrict__ xb, const float* __restrict__ Wi,
    const float* __restrict__ Wh, const float* __restrict__ bi,
    const float* __restrict__ bhn, char* __restrict__ exch,
    float* __restrict__ out) {
  __shared__ _Float16 Wh_l[48 * 512];
  __shared__ _Float16 Wi_l[48 * 512];
  __shared__ _Float16 Ah_l[16 * 512];
  __shared__ float Gh_l[2][3 * 256];
  __shared__ float Gx_l[2][3 * 256];

  const int tid = threadIdx.x;
  const int lane = tid & 63;
  const int wid = tid >> 6;
  const int g = blockIdx.x >> 5;
  const int rank = blockIdx.x & 31;
  const int c0 = rank * 16;
  char* const exg = exch + (size_t)g * 65536;

  for (int idx = tid; idx < 48 * 512; idx += 192) {
    int k = idx / 48;
    int r = idx - k * 48;
    int gate = r >> 4, j = r & 15;
    int col = gate * 512 + c0 + j;
    int phys = (r << 10) | ((((k >> 3) << 4) ^ ((r & 7) << 4))) | ((k & 7) << 1);
    *(_Float16*)((char*)Wi_l + phys) = (_Float16)Wi[(size_t)k * 1536 + col];
    *(_Float16*)((char*)Wh_l + phys) = (_Float16)Wh[(size_t)k * 1536 + col];
  }
  const int m0 = lane >> 3;
  const int cp = (lane & 7) * 2;
  float bir[2], biz[2], bin_[2], bh2[2];
#pragma unroll
  for (int u = 0; u < 2; ++u) {
    bir[u] = bi[c0 + cp + u];
    biz[u] = bi[512 + c0 + cp + u];
    bin_[u] = bi[1024 + c0 + cp + u];
    bh2[u] = bhn[c0 + cp + u];
  }
  float hreg[2][2] = {{0.f, 0.f}, {0.f, 0.f}};
  __syncthreads();

  const int ar = lane & 15;
  const int kg = lane >> 4;
  const int wrow = wid * 16 + ar;
  const int axor = (ar & 7) << 4;
  const int abase = ar << 10;
  const _Float16* const xrow = xb + (size_t)(g * 16 + ar) * (TLEN * DDIM);
  char* const hbase = exg + ((kg >> 1) * 512 + ar * 32 + (kg & 1) * 16);

  for (int t = 0; t < TLEN; ++t) {
    if (wid == 2) {
      unsigned* rst = (unsigned*)(exg + ((t + 2) & 3) * 16384 + rank * 512);
      __hip_atomic_store(rst + lane, SENT32, __ATOMIC_RELAXED, __HIP_MEMORY_SCOPE_AGENT);
      __hip_atomic_store(rst + 64 + lane, SENT32, __ATOMIC_RELAXED,
                         __HIP_MEMORY_SCOPE_AGENT);
    }
    half8 a_x[16];
    const half8* xs = (const half8*)(xrow + (size_t)t * DDIM);
#pragma unroll
    for (int kt = 0; kt < 16; ++kt) a_x[kt] = xs[kt * 4 + kg];
    f32x4 acc_x = {0.f, 0.f, 0.f, 0.f};
#pragma unroll
    for (int kt = 0; kt < 16; ++kt) {
      const int off = (((kt * 4 + kg) << 4) ^ axor);
      half8 b_i = *(const half8*)((const char*)Wi_l + (wrow << 10) + off);
      acc_x = __builtin_amdgcn_mfma_f32_16x16x32_f16(a_x[kt], b_i, acc_x, 0, 0, 0);
    }
    if (wid == 1 && t > 0) {
      char* hb = hbase + (t & 3) * 16384;
      const char* p0 = hb;
      const char* p1 = hb + 4096;
      const char* p2 = hb + 8192;
      const char* p3 = hb + 12288;
      half8 ah[16];
      unsigned dirty;
      int guard = 0;
      do {
        SWEEP16(ah, p0, p1, p2, p3);
        dirty = chk16(ah);
      } while (__any(dirty != 0u) && ++guard < GUARD);
#pragma unroll
      for (int kt = 0; kt < 16; ++kt)
        *(half8*)((char*)Ah_l + (abase | ((kt * 64 + kg * 16) ^ axor))) = ah[kt];
    }
    __syncthreads();
    f32x4 acc_h = {0.f, 0.f, 0.f, 0.f};
    if (t > 0) {
#pragma unroll
      for (int kt = 0; kt < 16; ++kt) {
        half8 a_h = *(const half8*)((const char*)Ah_l +
                                    (abase | ((kt * 64 + kg * 16) ^ axor)));
        const int off = (((kt * 4 + kg) << 4) ^ axor);
        half8 b_h = *(const half8*)((const char*)Wh_l + (wrow << 10) + off);
        acc_h = __builtin_amdgcn_mfma_f32_16x16x32_f16(a_h, b_h, acc_h, 0, 0, 0);
      }
    }
#pragma unroll
    for (int q = 0; q < 4; ++q) {
      int row = kg * 4 + q;
      Gh_l[t & 1][wid * 256 + row * 16 + ar] = acc_h[q];
      Gx_l[t & 1][wid * 256 + row * 16 + ar] = acc_x[q];
    }
    __syncthreads();
    if (wid == 0) {
      const float* GhT = Gh_l[t & 1];
      const float* GxT = Gx_l[t & 1];
      char* pub = exg + ((t + 1) & 3) * 16384 + rank * 512;
      float hn2[2][2];
#pragma unroll
      for (int bsel = 0; bsel < 2; ++bsel) {
        const int mm = m0 + 8 * bsel;
#pragma unroll
        for (int u = 0; u < 2; ++u) {
          const int gi_ = mm * 16 + cp + u;
          float r = sigmf(GxT[gi_] + GhT[gi_] + bir[u]);
          float z = sigmf(GxT[256 + gi_] + GhT[256 + gi_] + biz[u]);
          float pren = GxT[512 + gi_] + bin_[u] + r * (GhT[512 + gi_] + bh2[u]);
          float n = 2.f / (1.f + __expf(-2.f * pren)) - 1.f;
          hn2[bsel][u] = (1.f - z) * n + z * hreg[bsel][u];
          hreg[bsel][u] = hn2[bsel][u];
        }
        _Float16 q0 = (_Float16)hn2[bsel][0], q1 = (_Float16)hn2[bsel][1];
        unsigned pu = ((unsigned)*(unsigned short*)&q1 << 16) | *(unsigned short*)&q0;
        __hip_atomic_store((unsigned*)(pub + mm * 32 + cp * 2), pu, __ATOMIC_RELAXED,
                           __HIP_MEMORY_SCOPE_AGENT);
      }
#pragma unroll
      for (int bsel = 0; bsel < 2; ++bsel) {
        const int b = g * 16 + m0 + 8 * bsel;
        *(float2*)(out + ((size_t)b * TLEN + t) * HDIM + c0 + cp) =
            make_float2(hn2[bsel][0], hn2[bsel][1]);
      }
    }
  }
  if (wid == 0) {
#pragma unroll
    for (int bsel = 0; bsel < 2; ++bsel) {
      const int b = g * 16 + m0 + 8 * bsel;
      *(float2*)(out + (size_t)BSZ * TLEN * HDIM + (size_t)b * HDIM + c0 + cp) =
          make_float2(hreg[bsel][0], hreg[bsel][1]);
    }
  }
}

// ============================ launch =====================================

extern "C" void kernel_launch(void* const* d_in, const int* in_sizes, int n_in,
                              void* d_out, int out_size, void* d_ws, size_t ws_size,
                              hipStream_t stream) {
  const float* x = (const float*)d_in[0];
  const float* Wi = (const float*)d_in[1];
  const float* bi = (const float*)d_in[2];
  const float* Wh = (const float*)d_in[3];
  const float* bhn = (const float*)d_in[4];
  float* out = (float*)d_out;
  char* ws = (char*)d_ws;

  const size_t GI_BYTES = (size_t)BSZ * TLEN * 1536 * 2;  // 100,663,296
  const size_t NEED = GI_BYTES + 262144;

  if (ws_size >= NEED) {
    // fast path: gi at 0, exch after
    _Float16* gi = (_Float16*)ws;
    char* exch = ws + GI_BYTES;
    setup_fast<<<256, 256, 0, stream>>>((unsigned*)exch);
    gemm_gi<<<512, 384, 0, stream>>>(x, Wi, bi, gi);
    gru_rec16<<<64, 384, 0, stream>>>(gi, Wh, bhn, exch, out);
  } else {
    // fallback: r8 layout -- xb 33554432 | exch 262144
    _Float16* xb = (_Float16*)ws;
    char* exch = ws + 33554432;
    gru_setup<<<4096, 256, 0, stream>>>(x, xb, (unsigned*)exch);
    gru_rec<<<4 * 32, 192, 0, stream>>>(xb, Wi, Wh, bi, bhn, exch, out);
  }
}

// Round 16
// 1743.856 us; speedup vs baseline: 1.2142x; 1.2142x over previous
//
#include <hip/hip_runtime.h>

// GRU (Flax GRUCell), B=64 T=512 D=512 H=512, fp32 in/out, fp16 MFMA compute.
//
// FINAL = r8 verbatim (best measured: 1713us, 3.35us/step; absmax 3.9e-3).
//
// Structure: 4 groups x 16 batches x 32 blocks. Per-step h exchange via
// SENTINEL-CODED DATA POLLING on the sc1/agent transport: |h|<1 strictly
// (induction: h0=0, tanh/sigmoid-bounded updates), so fp16 0x4000 (2.0) is
// unreachable; a single poller wave reads the exchange data itself until
// sentinel-free -- discovery and data transfer are the same operation. No
// flags, no publish-side fences. 4-slot rotation; owner resets its own
// region 2 slots ahead (drift bound <=1 step). Poller broadcasts fragments
// via XOR-swizzled LDS; 2 barriers/step. All poll loops bounded (no hang).
//
// Campaign record (r7-r15): step time is INVARIANT to poller count (r14),
// per-step compute (r14), and every protocol micro-variant (r9-r12,r15).
// The ~2.7us/step wait is store->L3-visibility + discovery RTT on the
// coherence fabric -- a sequential-dependency latency floor, not a resource
// roofline (MfmaUtil 2.4%, HBM 3%). sc0 fast paths don't exist (r3-r5:
// sc0 is CU-scope; no XCD-L2 coherence scope on gfx950).
//
// Block: 192 thr; waves = gates r,z,n; w0 also combines+publishes+out,
// w1 also polls+stages, w2 also resets. 128 blocks x 124KB LDS -> 1/CU.

#define BSZ 64
#define TLEN 512
#define DDIM 512
#define HDIM 512
#define NGRP 4
#define PBLK 32
#define GB 16
#define SLOTB 16384   // bytes per slot per group: 32 ranks * 512B
#define GRPB 65536    // 4 slots
#define SENT32 0x40004000u
#define GUARD (1 << 16)

typedef _Float16 half8 __attribute__((ext_vector_type(8)));
typedef _Float16 half4v __attribute__((ext_vector_type(4)));
typedef float f32x4 __attribute__((ext_vector_type(4)));

__device__ __forceinline__ float sigmf(float v) { return 1.f / (1.f + __expf(-v)); }

// ---------------- setup: x fp32->fp16; fill exchange with sentinel
__global__ void gru_setup(const float* __restrict__ x, _Float16* __restrict__ xb,
                          unsigned* __restrict__ exch) {
  size_t gid = (size_t)blockIdx.x * blockDim.x + threadIdx.x;
  size_t stride = (size_t)gridDim.x * blockDim.x;
  const float4* x4 = (const float4*)x;
  size_t nx4 = (size_t)BSZ * TLEN * DDIM / 4;
  for (size_t i = gid; i < nx4; i += stride) {
    float4 v = x4[i];
    half4v o = {(_Float16)v.x, (_Float16)v.y, (_Float16)v.z, (_Float16)v.w};
    *(half4v*)(xb + 4 * i) = o;
  }
  for (size_t i = gid; i < (size_t)NGRP * GRPB / 4; i += stride) exch[i] = SENT32;
}

// dirty-chunk mask: dword low half == sentinel? (each 4B writer store covers
// 2 fp16 atomically, so per-dword low-half check is partial-write-safe)
__device__ __forceinline__ unsigned chk16(const half8* ah) {
  unsigned dirty = 0;
#pragma unroll
  for (int kt = 0; kt < 16; ++kt) {
    uint4 c;
    __builtin_memcpy(&c, &ah[kt], 16);
    unsigned bad = ((c.x & 0xFFFFu) == 0x4000u) | ((c.y & 0xFFFFu) == 0x4000u) |
                   ((c.z & 0xFFFFu) == 0x4000u) | ((c.w & 0xFFFFu) == 0x4000u);
    dirty |= bad << kt;
  }
  return dirty;
}

// ---------------- recurrence
__global__ __launch_bounds__(192, 1) void gru_rec(
    const _Float16* __restrict__ xb, const float* __restrict__ Wi,
    const float* __restrict__ Wh, const float* __restrict__ bi,
    const float* __restrict__ bhn, char* __restrict__ exch,
    float* __restrict__ out) {
  // LDS: weights 2x48KB + Ah staging 16KB + gate tiles 2x2x3KB = 124KB
  __shared__ _Float16 Wh_l[48 * 512];
  __shared__ _Float16 Wi_l[48 * 512];
  __shared__ _Float16 Ah_l[16 * 512];
  __shared__ float Gh_l[2][3 * 256];
  __shared__ float Gx_l[2][3 * 256];

  const int tid = threadIdx.x;
  const int lane = tid & 63;
  const int wid = tid >> 6;  // gate index; also role index
  const int g = blockIdx.x >> 5;
  const int rank = blockIdx.x & 31;
  const int c0 = rank * 16;
  char* const exg = exch + (size_t)g * GRPB;

  // --- one-time in-kernel weight transpose+convert into swizzled LDS
  // element k of row r at byte (r<<10) | (((k>>3)<<4)^((r&7)<<4)) | ((k&7)<<1)
  for (int idx = tid; idx < 48 * 512; idx += 192) {
    int k = idx / 48;
    int r = idx - k * 48;
    int gate = r >> 4, j = r & 15;
    int col = gate * 512 + c0 + j;
    int phys = (r << 10) | ((((k >> 3) << 4) ^ ((r & 7) << 4))) | ((k & 7) << 1);
    *(_Float16*)((char*)Wi_l + phys) = (_Float16)Wi[(size_t)k * 1536 + col];
    *(_Float16*)((char*)Wh_l + phys) = (_Float16)Wh[(size_t)k * 1536 + col];
  }

  // combine-lane mapping (wave0): batches {m0, m0+8}, cols {cp, cp+1}
  const int m0 = lane >> 3;       // 0..7
  const int cp = (lane & 7) * 2;  // 0,2,...,14
  float bir[2], biz[2], bin_[2], bh2[2];
#pragma unroll
  for (int u = 0; u < 2; ++u) {
    bir[u] = bi[c0 + cp + u];
    biz[u] = bi[512 + c0 + cp + u];
    bin_[u] = bi[1024 + c0 + cp + u];
    bh2[u] = bhn[c0 + cp + u];
  }
  float hreg[2][2] = {{0.f, 0.f}, {0.f, 0.f}};
  __syncthreads();  // weights staged

  const int ar = lane & 15;  // A row (batch) / B col-in-slice
  const int kg = lane >> 4;  // k-group
  const int wrow = wid * 16 + ar;
  const int axor = (ar & 7) << 4;
  const int abase = ar << 10;
  const _Float16* const xrow = xb + (size_t)(g * GB + ar) * (TLEN * DDIM);
  // exchange chunk kt for lane (ar,kg): hbase + slot*SLOTB + kt*1024
  // (each chunk = wave-contiguous 1KB window = 16 fully-consumed lines)
  char* const hbase = exg + ((kg >> 1) * 512 + ar * 32 + (kg & 1) * 16);

  for (int t = 0; t < TLEN; ++t) {
    // 0. w2: reset own region in slot t+2 (fire-and-forget; drained by this
    //    wave's vmcnt(0) at the step barrier, before slot republish at t+1)
    if (wid == 2) {
      unsigned* rst = (unsigned*)(exg + ((t + 2) & 3) * SLOTB + rank * 512);
      __hip_atomic_store(rst + lane, SENT32, __ATOMIC_RELAXED, __HIP_MEMORY_SCOPE_AGENT);
      __hip_atomic_store(rst + 64 + lane, SENT32, __ATOMIC_RELAXED,
                         __HIP_MEMORY_SCOPE_AGENT);
    }

    // 1. x fragments + x-GEMM (all waves; overlaps publish visibility)
    half8 a_x[16];
    const half8* xs = (const half8*)(xrow + (size_t)t * DDIM);
#pragma unroll
    for (int kt = 0; kt < 16; ++kt) a_x[kt] = xs[kt * 4 + kg];
    f32x4 acc_x = {0.f, 0.f, 0.f, 0.f};
#pragma unroll
    for (int kt = 0; kt < 16; ++kt) {
      const int off = (((kt * 4 + kg) << 4) ^ axor);
      half8 b_i = *(const half8*)((const char*)Wi_l + (wrow << 10) + off);
      acc_x = __builtin_amdgcn_mfma_f32_16x16x32_f16(a_x[kt], b_i, acc_x, 0, 0, 0);
    }

    // 2. w1: sweep until sentinel-free, then stage to LDS. Each sweep is 16
    //    pipelined loads + ONE vmcnt inside a single asm block (the only
    //    register-lifetime-safe form -- r15's split issue/wait corrupted
    //    in-flight destination registers).
    if (wid == 1 && t > 0) {
      char* hb = hbase + (t & 3) * SLOTB;
      const char* p0 = hb;
      const char* p1 = hb + 4096;
      const char* p2 = hb + 8192;
      const char* p3 = hb + 12288;
      half8 ah[16];
      unsigned dirty;
      int guard = 0;
      do {
        asm volatile(
            "global_load_dwordx4 %0,  %16, off sc1\n\t"
            "global_load_dwordx4 %1,  %16, off offset:1024 sc1\n\t"
            "global_load_dwordx4 %2,  %16, off offset:2048 sc1\n\t"
            "global_load_dwordx4 %3,  %16, off offset:3072 sc1\n\t"
            "global_load_dwordx4 %4,  %17, off sc1\n\t"
            "global_load_dwordx4 %5,  %17, off offset:1024 sc1\n\t"
            "global_load_dwordx4 %6,  %17, off offset:2048 sc1\n\t"
            "global_load_dwordx4 %7,  %17, off offset:3072 sc1\n\t"
            "global_load_dwordx4 %8,  %18, off sc1\n\t"
            "global_load_dwordx4 %9,  %18, off offset:1024 sc1\n\t"
            "global_load_dwordx4 %10, %18, off offset:2048 sc1\n\t"
            "global_load_dwordx4 %11, %18, off offset:3072 sc1\n\t"
            "global_load_dwordx4 %12, %19, off sc1\n\t"
            "global_load_dwordx4 %13, %19, off offset:1024 sc1\n\t"
            "global_load_dwordx4 %14, %19, off offset:2048 sc1\n\t"
            "global_load_dwordx4 %15, %19, off offset:3072 sc1\n\t"
            "s_waitcnt vmcnt(0)"
            : "=&v"(ah[0]), "=&v"(ah[1]), "=&v"(ah[2]), "=&v"(ah[3]),
              "=&v"(ah[4]), "=&v"(ah[5]), "=&v"(ah[6]), "=&v"(ah[7]),
              "=&v"(ah[8]), "=&v"(ah[9]), "=&v"(ah[10]), "=&v"(ah[11]),
              "=&v"(ah[12]), "=&v"(ah[13]), "=&v"(ah[14]), "=&v"(ah[15])
            : "v"(p0), "v"(p1), "v"(p2), "v"(p3));
        dirty = chk16(ah);
      } while (__any(dirty != 0u) && ++guard < GUARD);  // bounded: no hang
      // stage chunk (kt,kg) -> logical h[ar][kt*32+kg*8], XOR-swizzled
#pragma unroll
      for (int kt = 0; kt < 16; ++kt) {
        *(half8*)((char*)Ah_l + (abase | ((kt * 64 + kg * 16) ^ axor))) = ah[kt];
      }
    }
    __syncthreads();  // barrier1: Ah_l ready (and w2's resets drained)

    // 3. h-GEMM from LDS fragments
    f32x4 acc_h = {0.f, 0.f, 0.f, 0.f};
    if (t > 0) {
#pragma unroll
      for (int kt = 0; kt < 16; ++kt) {
        half8 a_h = *(const half8*)((const char*)Ah_l +
                                    (abase | ((kt * 64 + kg * 16) ^ axor)));
        const int off = (((kt * 4 + kg) << 4) ^ axor);
        half8 b_h = *(const half8*)((const char*)Wh_l + (wrow << 10) + off);
        acc_h = __builtin_amdgcn_mfma_f32_16x16x32_f16(a_h, b_h, acc_h, 0, 0, 0);
      }
    }
    // publish gate tiles (double-buffered; D layout col=ar, row=kg*4+q)
#pragma unroll
    for (int q = 0; q < 4; ++q) {
      int row = kg * 4 + q;
      Gh_l[t & 1][wid * 256 + row * 16 + ar] = acc_h[q];
      Gx_l[t & 1][wid * 256 + row * 16 + ar] = acc_x[q];
    }
    __syncthreads();  // barrier2: gates(t) ready

    // 4. combine + publish (wave 0): fire-and-forget sentinel-coded data
    if (wid == 0) {
      const float* GhT = Gh_l[t & 1];
      const float* GxT = Gx_l[t & 1];
      char* pub = exg + ((t + 1) & 3) * SLOTB + rank * 512;
      float hn2[2][2];
#pragma unroll
      for (int bsel = 0; bsel < 2; ++bsel) {
        const int m = m0 + 8 * bsel;
#pragma unroll
        for (int u = 0; u < 2; ++u) {
          const int gi_ = m * 16 + cp + u;
          float r = sigmf(GxT[gi_] + GhT[gi_] + bir[u]);
          float z = sigmf(GxT[256 + gi_] + GhT[256 + gi_] + biz[u]);
          float pren = GxT[512 + gi_] + bin_[u] + r * (GhT[512 + gi_] + bh2[u]);
          float n = 2.f / (1.f + __expf(-2.f * pren)) - 1.f;
          hn2[bsel][u] = (1.f - z) * n + z * hreg[bsel][u];
          hreg[bsel][u] = hn2[bsel][u];
        }
        _Float16 q0 = (_Float16)hn2[bsel][0], q1 = (_Float16)hn2[bsel][1];
        unsigned pu = ((unsigned)*(unsigned short*)&q1 << 16) | *(unsigned short*)&q0;
        __hip_atomic_store((unsigned*)(pub + m * 32 + cp * 2), pu, __ATOMIC_RELAXED,
                           __HIP_MEMORY_SCOPE_AGENT);
      }
      // out stores after the publishes (off the critical path)
#pragma unroll
      for (int bsel = 0; bsel < 2; ++bsel) {
        const int b = g * GB + m0 + 8 * bsel;
        *(float2*)(out + ((size_t)b * TLEN + t) * HDIM + c0 + cp) =
            make_float2(hn2[bsel][0], hn2[bsel][1]);
      }
    }
  }

  // carry output: final h
  if (wid == 0) {
#pragma unroll
    for (int bsel = 0; bsel < 2; ++bsel) {
      const int b = g * GB + m0 + 8 * bsel;
      *(float2*)(out + (size_t)BSZ * TLEN * HDIM + (size_t)b * HDIM + c0 + cp) =
          make_float2(hreg[bsel][0], hreg[bsel][1]);
    }
  }
}

extern "C" void kernel_launch(void* const* d_in, const int* in_sizes, int n_in,
                              void* d_out, int out_size, void* d_ws, size_t ws_size,
                              hipStream_t stream) {
  const float* x = (const float*)d_in[0];
  const float* Wi = (const float*)d_in[1];
  const float* bi = (const float*)d_in[2];
  const float* Wh = (const float*)d_in[3];
  const float* bhn = (const float*)d_in[4];
  float* out = (float*)d_out;

  // ws layout (bytes): xb 33554432 | exch 262144  (total 33.8MB, proven-safe)
  char* ws = (char*)d_ws;
  _Float16* xb = (_Float16*)ws;
  char* exch = ws + 33554432;

  gru_setup<<<4096, 256, 0, stream>>>(x, xb, (unsigned*)exch);
  gru_rec<<<NGRP * PBLK, 192, 0, stream>>>(xb, Wi, Wh, bi, bhn, exch, out);
}